// Round 4
// baseline (954.479 us; speedup 1.0000x reference)
//
#include <hip/hip_runtime.h>

// ---- problem constants (from reference) ----
#define N_LANEC  20000
#define N_AGENTC 4000
#define PTS      20
#define FD       8
#define HD       128
#define E_LLC    640000
#define E_AAC    128000
#define E_LAC    200000

typedef unsigned short u16;
typedef unsigned int   u32;

__device__ __forceinline__ float bf2f(u16 u) {
    union { u32 i; float f; } c; c.i = ((u32)u) << 16; return c.f;
}
__device__ __forceinline__ u16 f2bf(float f) {
    union { float f; u32 i; } c; c.f = f;
    u32 r = c.i + 0x7FFFu + ((c.i >> 16) & 1u);   // RNE
    return (u16)(r >> 16);
}
// dtype-polymorphic float load: isf=1 -> fp32 buffer, isf=0 -> bf16 buffer
__device__ __forceinline__ float ldf(const void* p, size_t i, int isf) {
    return isf ? ((const float*)p)[i] : bf2f(((const u16*)p)[i]);
}

// ---------------------------------------------------------------------------
// input dtype detection on N(0,1) data (bf16 vs fp32), see round-2 notes
// ---------------------------------------------------------------------------
__global__ void detect_kernel(const u32* __restrict__ x, int* __restrict__ flag) {
    __shared__ int cnt;
    if (threadIdx.x == 0) cnt = 0;
    __syncthreads();
    u32 w = x[threadIdx.x];
    int e = (int)((w >> 7) & 0xFFu);
    int ok = (e == 0) || (e >= 100 && e <= 140);
    atomicAdd(&cnt, ok);
    __syncthreads();
    if (threadIdx.x == 0) *flag = (cnt >= 200) ? 0 : 1;   // 1 = fp32 inputs
}

// ---------------------------------------------------------------------------
// PointNet-style encoder: x[n][20][8] -> out[n][128] (bf16 out, ws buffer)
// ---------------------------------------------------------------------------
__global__ __launch_bounds__(256) void encode_kernel(
    const void* __restrict__ x,
    const void* __restrict__ w1, const void* __restrict__ b1,
    const void* __restrict__ w2, const void* __restrict__ b2,
    const void* __restrict__ w3, const void* __restrict__ b3,
    u16* __restrict__ out, const int* __restrict__ dflag)
{
    const int NT = 4;
    __shared__ float xs[NT][PTS][FD];
    __shared__ float h1s[NT][PTS][HD];
    __shared__ float ms[NT][HD];
    __shared__ float refs[NT][2];

    const int isf = *dflag;
    const int tid = threadIdx.x;
    const int j = tid & (HD - 1);
    const int g = tid >> 7;
    const int n0 = blockIdx.x * NT;

    float* xsf = &xs[0][0][0];
    for (int idx = tid; idx < NT * PTS * FD; idx += 256)
        xsf[idx] = ldf(x, (size_t)n0 * PTS * FD + idx, isf);
    __syncthreads();
    if (tid < NT * 2) refs[tid >> 1][tid & 1] = xs[tid >> 1][PTS - 1][tid & 1];
    __syncthreads();
    for (int idx = tid; idx < NT * PTS * 2; idx += 256) {
        int nn = idx / (PTS * 2); int r = idx - nn * PTS * 2;
        xs[nn][r >> 1][r & 1] -= refs[nn][r & 1];
    }
    __syncthreads();

    // ---- layer 1 (K=8) ----
    float w1c[FD];
    #pragma unroll
    for (int k = 0; k < FD; k++) w1c[k] = ldf(w1, k * HD + j, isf);
    const float b1j = ldf(b1, j, isf);
    float acc[2][PTS];
    #pragma unroll
    for (int nn = 0; nn < 2; nn++)
        #pragma unroll
        for (int t = 0; t < PTS; t++) acc[nn][t] = b1j;
    #pragma unroll
    for (int k = 0; k < FD; k++) {
        float w = w1c[k];
        #pragma unroll
        for (int nn = 0; nn < 2; nn++)
            #pragma unroll
            for (int t = 0; t < PTS; t++)
                acc[nn][t] += xs[g * 2 + nn][t][k] * w;
    }
    #pragma unroll
    for (int nn = 0; nn < 2; nn++)
        #pragma unroll
        for (int t = 0; t < PTS; t++)
            h1s[g * 2 + nn][t][j] = fmaxf(acc[nn][t], 0.f);
    __syncthreads();

    // ---- layer 2 (K=128) ----
    const float b2j = ldf(b2, j, isf);
    #pragma unroll
    for (int nn = 0; nn < 2; nn++)
        #pragma unroll
        for (int t = 0; t < PTS; t++) acc[nn][t] = b2j;
    for (int k4 = 0; k4 < HD / 4; k4++) {
        const int k = k4 * 4;
        const float wa = ldf(w2, (k + 0) * HD + j, isf);
        const float wb = ldf(w2, (k + 1) * HD + j, isf);
        const float wc = ldf(w2, (k + 2) * HD + j, isf);
        const float wd = ldf(w2, (k + 3) * HD + j, isf);
        #pragma unroll
        for (int nn = 0; nn < 2; nn++)
            #pragma unroll
            for (int t = 0; t < PTS; t++) {
                const float4 h4 = *(const float4*)&h1s[g * 2 + nn][t][k];
                acc[nn][t] += h4.x * wa + h4.y * wb + h4.z * wc + h4.w * wd;
            }
    }
    #pragma unroll
    for (int nn = 0; nn < 2; nn++) {
        float m = 0.f;   // max(relu(.)) == relu(max(.))
        #pragma unroll
        for (int t = 0; t < PTS; t++) m = fmaxf(m, acc[nn][t]);
        ms[g * 2 + nn][j] = m;
    }
    __syncthreads();

    // ---- layer 3 (K=128) ----
    const float b3j = ldf(b3, j, isf);
    float a3[2] = { b3j, b3j };
    for (int k4 = 0; k4 < HD / 4; k4++) {
        const int k = k4 * 4;
        const float wa = ldf(w3, (k + 0) * HD + j, isf);
        const float wb = ldf(w3, (k + 1) * HD + j, isf);
        const float wc = ldf(w3, (k + 2) * HD + j, isf);
        const float wd = ldf(w3, (k + 3) * HD + j, isf);
        #pragma unroll
        for (int nn = 0; nn < 2; nn++) {
            const float4 m4 = *(const float4*)&ms[g * 2 + nn][k];
            a3[nn] += m4.x * wa + m4.y * wb + m4.z * wc + m4.w * wd;
        }
    }
    #pragma unroll
    for (int nn = 0; nn < 2; nn++)
        out[(size_t)(n0 + g * 2 + nn) * HD + j] = f2bf(fmaxf(a3[nn], 0.f));
}

// ---------------------------------------------------------------------------
// Edge GNN MLP: out = node + relu(relu([node,agg]@w1+b1)@w2+b2)
// node: bf16 (ws). agg: fp32 (d_out region, may alias out). out: fp32 or bf16.
// In-place safe: each block only reads its own rows before its final writes.
// ---------------------------------------------------------------------------
template<int OUT_BF16>
__global__ __launch_bounds__(256) void gnn_kernel(
    const u16* node, const float* agg,
    const void* __restrict__ w1, const void* __restrict__ b1,
    const void* __restrict__ w2, const void* __restrict__ b2,
    void* outv, const int* __restrict__ dflag)
{
    const int NT = 8;
    __shared__ float cats[NT][2 * HD];
    __shared__ float hs[NT][HD];
    const int isf = *dflag;
    const int tid = threadIdx.x;
    const int j = tid & (HD - 1);
    const int g = tid >> 7;
    const int n0 = blockIdx.x * NT;

    for (int idx = tid; idx < NT * 2 * HD; idx += 256) {
        int nn = idx >> 8; int k = idx & 255;
        cats[nn][k] = (k < HD) ? bf2f(node[(size_t)(n0 + nn) * HD + k])
                               : agg[(size_t)(n0 + nn) * HD + (k - HD)];
    }
    __syncthreads();

    const float b1j = ldf(b1, j, isf);
    float acc[4] = { b1j, b1j, b1j, b1j };
    for (int k4 = 0; k4 < (2 * HD) / 4; k4++) {
        const int k = k4 * 4;
        const float wa = ldf(w1, (k + 0) * HD + j, isf);
        const float wb = ldf(w1, (k + 1) * HD + j, isf);
        const float wc = ldf(w1, (k + 2) * HD + j, isf);
        const float wd = ldf(w1, (k + 3) * HD + j, isf);
        #pragma unroll
        for (int nn = 0; nn < 4; nn++) {
            const float4 c4 = *(const float4*)&cats[g * 4 + nn][k];
            acc[nn] += c4.x * wa + c4.y * wb + c4.z * wc + c4.w * wd;
        }
    }
    #pragma unroll
    for (int nn = 0; nn < 4; nn++) hs[g * 4 + nn][j] = fmaxf(acc[nn], 0.f);
    __syncthreads();

    const float b2j = ldf(b2, j, isf);
    float a2[4] = { b2j, b2j, b2j, b2j };
    for (int k4 = 0; k4 < HD / 4; k4++) {
        const int k = k4 * 4;
        const float wa = ldf(w2, (k + 0) * HD + j, isf);
        const float wb = ldf(w2, (k + 1) * HD + j, isf);
        const float wc = ldf(w2, (k + 2) * HD + j, isf);
        const float wd = ldf(w2, (k + 3) * HD + j, isf);
        #pragma unroll
        for (int nn = 0; nn < 4; nn++) {
            const float4 h4 = *(const float4*)&hs[g * 4 + nn][k];
            a2[nn] += h4.x * wa + h4.y * wb + h4.z * wc + h4.w * wd;
        }
    }
    #pragma unroll
    for (int nn = 0; nn < 4; nn++) {
        size_t o = (size_t)(n0 + g * 4 + nn) * HD + j;
        float res = bf2f(node[o]) + fmaxf(a2[nn], 0.f);
        if (OUT_BF16) ((u16*)outv)[o] = f2bf(res);
        else          ((float*)outv)[o] = res;
    }
}

// ---------------------------------------------------------------------------
// CSR mean aggregation, fp32 accumulate, fp32 output. src bf16 or fp32.
// ---------------------------------------------------------------------------
template<int SRC_F32>
__global__ __launch_bounds__(128) void agg_kernel(
    const void* srcv, const u16* __restrict__ col,
    const int* __restrict__ rowptr, float* agg)
{
    __shared__ int cbuf[128];
    const int d = blockIdx.x;
    const int j = threadIdx.x;
    const int beg = rowptr[d], end = rowptr[d + 1];
    float acc = 0.f;
    for (int base = beg; base < end; base += 128) {
        const int m = min(128, end - base);
        if (j < m) cbuf[j] = (int)col[base + j];
        __syncthreads();
        #pragma unroll 4
        for (int e = 0; e < m; e++) {
            size_t o = (size_t)cbuf[e] * HD + j;
            acc += SRC_F32 ? ((const float*)srcv)[o] : bf2f(((const u16*)srcv)[o]);
        }
        __syncthreads();
    }
    const float deg = (float)(end - beg);
    agg[(size_t)d * HD + j] = acc / fmaxf(deg, 1.f);
}

// ---------------------------------------------------------------------------
// CSR build helpers (counts accumulated into rp, scanned in place)
// ---------------------------------------------------------------------------
__global__ void zero_kernel(int* __restrict__ p, int n) {
    int i = blockIdx.x * blockDim.x + threadIdx.x;
    if (i < n) p[i] = 0;
}
__global__ void count_kernel(const int* __restrict__ dst, int* __restrict__ cnt, int ne) {
    int e = blockIdx.x * blockDim.x + threadIdx.x;
    if (e < ne) atomicAdd(&cnt[dst[e]], 1);
}
__global__ void fill_kernel(const int* __restrict__ src, const int* __restrict__ dst,
                            int* __restrict__ cur, u16* __restrict__ col, int ne) {
    int e = blockIdx.x * blockDim.x + threadIdx.x;
    if (e < ne) {
        int d = dst[e];
        int p = atomicAdd(&cur[d], 1);
        col[p] = (u16)src[e];
    }
}
__global__ void initcur_kernel(const int* __restrict__ rp_ll, const int* __restrict__ rp_aa,
                               const int* __restrict__ rp_la, int* __restrict__ cur) {
    int i = blockIdx.x * blockDim.x + threadIdx.x;
    if (i < N_LANEC) cur[i] = rp_ll[i];
    else if (i < N_LANEC + N_AGENTC) cur[i] = rp_aa[i - N_LANEC];
    else if (i < N_LANEC + 2 * N_AGENTC) cur[i] = rp_la[i - N_LANEC - N_AGENTC];
}

// in-place exclusive scan (LDS Hillis-Steele), one block per array
__global__ __launch_bounds__(1024) void scan3_kernel(
    int* __restrict__ rp_ll, int* __restrict__ rp_aa, int* __restrict__ rp_la)
{
    int* rp; int n;
    if (blockIdx.x == 0)      { rp = rp_ll; n = N_LANEC; }
    else if (blockIdx.x == 1) { rp = rp_aa; n = N_AGENTC; }
    else                      { rp = rp_la; n = N_AGENTC; }

    __shared__ int s[1024];
    __shared__ int carry;
    const int tid = threadIdx.x;
    if (tid == 0) carry = 0;
    __syncthreads();

    for (int base = 0; base < n; base += 1024) {
        const int i = base + tid;
        const int v = (i < n) ? rp[i] : 0;
        s[tid] = v;
        __syncthreads();
        for (int off = 1; off < 1024; off <<= 1) {
            int t = (tid >= off) ? s[tid - off] : 0;
            __syncthreads();
            s[tid] += t;
            __syncthreads();
        }
        const int incl = s[tid];
        const int c = carry;
        __syncthreads();
        if (i < n) rp[i] = c + incl - v;     // exclusive
        if (tid == 1023) carry = c + incl;
        __syncthreads();
    }
    if (tid == 0) rp[n] = carry;
}

// ---------------------------------------------------------------------------
extern "C" void kernel_launch(void* const* d_in, const int* in_sizes, int n_in,
                              void* d_out, int out_size, void* d_ws, size_t ws_size,
                              hipStream_t stream)
{
    const void* lane_pts   = d_in[0];
    const void* agent_hist = d_in[1];
    const int* e_ll = (const int*)d_in[2];   // [2][E]: row0 src, row1 dst
    const int* e_aa = (const int*)d_in[3];
    const int* e_la = (const int*)d_in[4];
    const void *lw1 = d_in[5],  *lb1 = d_in[6],  *lw2 = d_in[7],  *lb2 = d_in[8],
               *lw3 = d_in[9],  *lb3 = d_in[10];
    const void *aw1 = d_in[11], *ab1 = d_in[12], *aw2 = d_in[13], *ab2 = d_in[14],
               *aw3 = d_in[15], *ab3 = d_in[16];
    const void *llw1 = d_in[17], *llb1 = d_in[18], *llw2 = d_in[19], *llb2 = d_in[20];
    const void *aaw1 = d_in[21], *aab1 = d_in[22], *aaw2 = d_in[23], *aab2 = d_in[24];
    const void *law1 = d_in[25], *lab1 = d_in[26], *law2 = d_in[27], *lab2 = d_in[28];

    // ---- workspace layout, total ~8.30 MB (< 8 MiB) ----
    int* ip = (int*)d_ws;
    int* dflag = ip; ip += 4;
    int* rp_ll = ip; ip += N_LANEC + 1;      // counts -> exclusive rowptr (in place)
    int* rp_aa = ip; ip += N_AGENTC + 1;
    int* rp_la = ip; ip += N_AGENTC + 1;
    int* cur   = ip; ip += N_LANEC + 2 * N_AGENTC;
    u16* hp = (u16*)ip;
    u16* col_ll = hp; hp += E_LLC;
    u16* col_aa = hp; hp += E_AAC;
    u16* col_la = hp; hp += E_LAC;
    u16* lane_enc  = hp; hp += (size_t)N_LANEC * HD;   // bf16 encoder outputs
    u16* agent_enc = hp; hp += (size_t)N_AGENTC * HD;  // bf16; updated in place by aa-gnn

    // d_out is FP32: lane (20000x128) then agent (4000x128). Also used as
    // fp32 agg scratch before each gnn overwrites it in place.
    float* out_lane  = (float*)d_out;
    float* out_agent = (float*)d_out + (size_t)N_LANEC * HD;

    const int NRP  = (N_LANEC + 1) + 2 * (N_AGENTC + 1);  // 28003
    const int NCUR = N_LANEC + 2 * N_AGENTC;              // 28000

    detect_kernel<<<1, 256, 0, stream>>>((const u32*)lane_pts, dflag);

    // ---- CSR build ----
    zero_kernel<<<(NRP + 255) / 256, 256, 0, stream>>>(rp_ll, NRP);
    count_kernel<<<(E_LLC + 255) / 256, 256, 0, stream>>>(e_ll + E_LLC, rp_ll, E_LLC);
    count_kernel<<<(E_AAC + 255) / 256, 256, 0, stream>>>(e_aa + E_AAC, rp_aa, E_AAC);
    count_kernel<<<(E_LAC + 255) / 256, 256, 0, stream>>>(e_la + E_LAC, rp_la, E_LAC);
    scan3_kernel<<<3, 1024, 0, stream>>>(rp_ll, rp_aa, rp_la);
    initcur_kernel<<<(NCUR + 255) / 256, 256, 0, stream>>>(rp_ll, rp_aa, rp_la, cur);
    fill_kernel<<<(E_LLC + 255) / 256, 256, 0, stream>>>(e_ll, e_ll + E_LLC, cur,           col_ll, E_LLC);
    fill_kernel<<<(E_AAC + 255) / 256, 256, 0, stream>>>(e_aa, e_aa + E_AAC, cur + N_LANEC, col_aa, E_AAC);
    fill_kernel<<<(E_LAC + 255) / 256, 256, 0, stream>>>(e_la, e_la + E_LAC, cur + N_LANEC + N_AGENTC, col_la, E_LAC);

    // ---- encoders (bf16 features into ws) ----
    encode_kernel<<<N_LANEC / 4, 256, 0, stream>>>(lane_pts, lw1, lb1, lw2, lb2, lw3, lb3, lane_enc, dflag);
    encode_kernel<<<N_AGENTC / 4, 256, 0, stream>>>(agent_hist, aw1, ab1, aw2, ab2, aw3, ab3, agent_enc, dflag);

    // ---- lane-lane GNN: agg -> d_out lane region (fp32), gnn in place ----
    agg_kernel<0><<<N_LANEC, 128, 0, stream>>>(lane_enc, col_ll, rp_ll, out_lane);
    gnn_kernel<0><<<N_LANEC / 8, 256, 0, stream>>>(lane_enc, out_lane, llw1, llb1, llw2, llb2, out_lane, dflag);

    // ---- agent-agent GNN: agg -> d_out agent region; mid result back into
    //      agent_enc (bf16, in place w.r.t. node input — per-block rows) ----
    agg_kernel<0><<<N_AGENTC, 128, 0, stream>>>(agent_enc, col_aa, rp_aa, out_agent);
    gnn_kernel<1><<<N_AGENTC / 8, 256, 0, stream>>>(agent_enc, out_agent, aaw1, aab1, aaw2, aab2, agent_enc, dflag);

    // ---- lane->agent GNN: agg from FINAL lane (fp32) -> d_out agent region;
    //      final agent = agent_mid + relu(...), fp32 into d_out ----
    agg_kernel<1><<<N_AGENTC, 128, 0, stream>>>(out_lane, col_la, rp_la, out_agent);
    gnn_kernel<0><<<N_AGENTC / 8, 256, 0, stream>>>(agent_enc, out_agent, law1, lab1, law2, lab2, out_agent, dflag);
}

// Round 5
// 514.781 us; speedup vs baseline: 1.8541x; 1.8541x over previous
//
#include <hip/hip_runtime.h>

// ---- problem constants (from reference) ----
#define N_LANEC  20000
#define N_AGENTC 4000
#define PTS      20
#define FD       8
#define HD       128
#define E_LLC    640000
#define E_AAC    128000
#define E_LAC    200000

typedef unsigned short u16;
typedef unsigned int   u32;
typedef __attribute__((ext_vector_type(8))) short short8;   // 8 bf16 (4 VGPRs)
typedef __attribute__((ext_vector_type(4))) float f32x4;    // MFMA C/D

__device__ __forceinline__ float bf2f(u16 u) {
    union { u32 i; float f; } c; c.i = ((u32)u) << 16; return c.f;
}
__device__ __forceinline__ u16 f2bf(float f) {
    union { float f; u32 i; } c; c.f = f;
    u32 r = c.i + 0x7FFFu + ((c.i >> 16) & 1u);   // RNE
    return (u16)(r >> 16);
}
// dtype-polymorphic float load: isf=1 -> fp32 buffer, isf=0 -> bf16 buffer
__device__ __forceinline__ float ldf(const void* p, size_t i, int isf) {
    return isf ? ((const float*)p)[i] : bf2f(((const u16*)p)[i]);
}

// ---------------------------------------------------------------------------
// input dtype detection (bf16 vs fp32) — round-4 verified (chose fp32)
// ---------------------------------------------------------------------------
__global__ void detect_kernel(const u32* __restrict__ x, int* __restrict__ flag) {
    __shared__ int cnt;
    if (threadIdx.x == 0) cnt = 0;
    __syncthreads();
    u32 w = x[threadIdx.x];
    int e = (int)((w >> 7) & 0xFFu);
    int ok = (e == 0) || (e >= 100 && e <= 140);
    atomicAdd(&cnt, ok);
    __syncthreads();
    if (threadIdx.x == 0) *flag = (cnt >= 200) ? 0 : 1;   // 1 = fp32 inputs
}

// ---------------------------------------------------------------------------
// Weight swizzle to MFMA B-frag-major bf16: dst[((nt*KS+ks)*64+lane)*8+j] =
//   bf16( src[(ks*32+(lane>>4)*8+j)*128 + nt*16+(lane&15)] )
// so a wave's B-fragment for (nt,ks) is one coalesced 16B/lane load.
// ---------------------------------------------------------------------------
__global__ void swz_kernel(const void* __restrict__ src, u16* __restrict__ dst,
                           int kshift, int total, const int* __restrict__ dflag) {
    const int isf = *dflag;
    int idx = blockIdx.x * 256 + threadIdx.x;
    if (idx >= total) return;
    int j    = idx & 7;
    int lane = (idx >> 3) & 63;
    int t2   = idx >> 9;
    int ks   = t2 & ((1 << kshift) - 1);
    int nt   = t2 >> kshift;
    int k = ks * 32 + ((lane >> 4) << 3) + j;
    int n = nt * 16 + (lane & 15);
    dst[idx] = f2bf(ldf(src, (size_t)k * HD + n, isf));
}

// ---------------------------------------------------------------------------
// PointNet encoder: x[n][20][8] -> out[n][128] bf16.  4 nodes/block, 4 waves.
// Layer1 (K=8): VALU. Layer2 (80x128 @ 128x128): MFMA 16x16x32 bf16.
// Layer3 (K=128): VALU.  LDS ~48 KB.
// ---------------------------------------------------------------------------
__global__ __launch_bounds__(256) void encode_kernel(
    const void* __restrict__ x,
    const void* __restrict__ w1, const void* __restrict__ b1,
    const u16* __restrict__ w2s, const void* __restrict__ b2,
    const void* __restrict__ w3, const void* __restrict__ b3,
    u16* __restrict__ out, const int* __restrict__ dflag)
{
    const int NT = 4;                      // nodes per block, M = 80
    __shared__ float xs[NT][PTS][FD];
    __shared__ float refs[NT][2];
    __shared__ __align__(16) u16 a_lds[NT * PTS][HD + 8];   // h1 bf16, pad 8
    __shared__ __align__(16) u16 h2b[NT * PTS][HD + 8];     // h2 bf16
    __shared__ float ms[NT][HD];

    const int isf = *dflag;
    const int tid  = threadIdx.x;
    const int lane = tid & 63;
    const int wv   = tid >> 6;             // wave 0..3
    const int l15  = lane & 15;
    const int quad = lane >> 4;
    const int j = tid & (HD - 1);
    const int g = tid >> 7;
    const int n0 = blockIdx.x * NT;

    // ---- stage x, subtract last-point xy ref ----
    float* xsf = &xs[0][0][0];
    for (int idx = tid; idx < NT * PTS * FD; idx += 256)
        xsf[idx] = ldf(x, (size_t)n0 * PTS * FD + idx, isf);
    __syncthreads();
    if (tid < NT * 2) refs[tid >> 1][tid & 1] = xs[tid >> 1][PTS - 1][tid & 1];
    __syncthreads();
    for (int idx = tid; idx < NT * PTS * 2; idx += 256) {
        int nn = idx / (PTS * 2); int r = idx - nn * PTS * 2;
        xs[nn][r >> 1][r & 1] -= refs[nn][r & 1];
    }
    __syncthreads();

    // ---- layer 1 (K=8), VALU; write h1 bf16 to a_lds ----
    float w1c[FD];
    #pragma unroll
    for (int k = 0; k < FD; k++) w1c[k] = ldf(w1, k * HD + j, isf);
    const float b1j = ldf(b1, j, isf);
    float acc[2][PTS];
    #pragma unroll
    for (int nn = 0; nn < 2; nn++)
        #pragma unroll
        for (int t = 0; t < PTS; t++) acc[nn][t] = b1j;
    #pragma unroll
    for (int k = 0; k < FD; k++) {
        float w = w1c[k];
        #pragma unroll
        for (int nn = 0; nn < 2; nn++)
            #pragma unroll
            for (int t = 0; t < PTS; t++)
                acc[nn][t] += xs[g * 2 + nn][t][k] * w;
    }
    #pragma unroll
    for (int nn = 0; nn < 2; nn++)
        #pragma unroll
        for (int t = 0; t < PTS; t++)
            a_lds[(g * 2 + nn) * PTS + t][j] = f2bf(fmaxf(acc[nn][t], 0.f));
    __syncthreads();

    // ---- layer 2: MFMA. wave wv owns n-tiles {2wv, 2wv+1}, all 5 m-tiles ----
    short8 bfr[2][4];
    float b2v[2];
    #pragma unroll
    for (int nt2 = 0; nt2 < 2; nt2++) {
        const int ntg = wv * 2 + nt2;
        b2v[nt2] = ldf(b2, ntg * 16 + l15, isf);
        #pragma unroll
        for (int ks = 0; ks < 4; ks++)
            bfr[nt2][ks] = *(const short8*)&w2s[(((size_t)(ntg * 4 + ks)) * 64 + lane) * 8];
    }
    for (int mt = 0; mt < 5; mt++) {
        short8 af[4];
        #pragma unroll
        for (int ks = 0; ks < 4; ks++)
            af[ks] = *(const short8*)&a_lds[mt * 16 + l15][ks * 32 + quad * 8];
        #pragma unroll
        for (int nt2 = 0; nt2 < 2; nt2++) {
            f32x4 c = {0.f, 0.f, 0.f, 0.f};
            #pragma unroll
            for (int ks = 0; ks < 4; ks++)
                c = __builtin_amdgcn_mfma_f32_16x16x32_bf16(af[ks], bfr[nt2][ks], c, 0, 0, 0);
            const int col = (wv * 2 + nt2) * 16 + l15;
            #pragma unroll
            for (int r = 0; r < 4; r++)
                h2b[mt * 16 + quad * 4 + r][col] = f2bf(c[r] + b2v[nt2]);
        }
    }
    __syncthreads();

    // ---- max over t (relu folded: floor at 0) ----
    #pragma unroll
    for (int nn = 0; nn < 2; nn++) {
        float m = 0.f;
        #pragma unroll
        for (int t = 0; t < PTS; t++)
            m = fmaxf(m, bf2f(h2b[(g * 2 + nn) * PTS + t][j]));
        ms[g * 2 + nn][j] = m;
    }
    __syncthreads();

    // ---- layer 3 (K=128), VALU ----
    const float b3j = ldf(b3, j, isf);
    float a3[2] = { b3j, b3j };
    for (int k4 = 0; k4 < HD / 4; k4++) {
        const int k = k4 * 4;
        const float wa = ldf(w3, (k + 0) * HD + j, isf);
        const float wb = ldf(w3, (k + 1) * HD + j, isf);
        const float wc = ldf(w3, (k + 2) * HD + j, isf);
        const float wd = ldf(w3, (k + 3) * HD + j, isf);
        #pragma unroll
        for (int nn = 0; nn < 2; nn++) {
            const float4 m4 = *(const float4*)&ms[g * 2 + nn][k];
            a3[nn] += m4.x * wa + m4.y * wb + m4.z * wc + m4.w * wd;
        }
    }
    #pragma unroll
    for (int nn = 0; nn < 2; nn++)
        out[(size_t)(n0 + g * 2 + nn) * HD + j] = f2bf(fmaxf(a3[nn], 0.f));
}

// ---------------------------------------------------------------------------
// Edge GNN MLP via MFMA: out = node + relu(relu([node,agg]@w1+b1)@w2+b2)
// 16 nodes/block (M=16), 4 waves x 2 n-tiles. node bf16, agg fp32 (may alias
// out). In-place safe: block only reads its own rows before its writes.
// ---------------------------------------------------------------------------
template<int OUT_BF16>
__global__ __launch_bounds__(256) void gnn_kernel(
    const u16* node, const float* agg,
    const u16* __restrict__ w1s, const void* __restrict__ b1,
    const u16* __restrict__ w2s, const void* __restrict__ b2,
    void* outv, const int* __restrict__ dflag)
{
    __shared__ __align__(16) u16 cats[16][2 * HD + 8];
    __shared__ __align__(16) u16 hb[16][HD + 8];
    const int isf = *dflag;
    const int tid  = threadIdx.x;
    const int lane = tid & 63;
    const int wv   = tid >> 6;
    const int l15  = lane & 15;
    const int quad = lane >> 4;
    const int n0 = blockIdx.x * 16;

    for (int idx = tid; idx < 16 * 2 * HD; idx += 256) {
        int nn = idx >> 8; int k = idx & 255;
        cats[nn][k] = (k < HD) ? node[(size_t)(n0 + nn) * HD + k]
                               : f2bf(agg[(size_t)(n0 + nn) * HD + (k - HD)]);
    }
    __syncthreads();

    // ---- layer 1: K=256 ----
    #pragma unroll
    for (int nt2 = 0; nt2 < 2; nt2++) {
        const int ntg = wv * 2 + nt2;
        const float b1v = ldf(b1, ntg * 16 + l15, isf);
        f32x4 c = {0.f, 0.f, 0.f, 0.f};
        #pragma unroll
        for (int ks = 0; ks < 8; ks++) {
            short8 a = *(const short8*)&cats[l15][ks * 32 + quad * 8];
            short8 b = *(const short8*)&w1s[(((size_t)(ntg * 8 + ks)) * 64 + lane) * 8];
            c = __builtin_amdgcn_mfma_f32_16x16x32_bf16(a, b, c, 0, 0, 0);
        }
        #pragma unroll
        for (int r = 0; r < 4; r++)
            hb[quad * 4 + r][ntg * 16 + l15] = f2bf(fmaxf(c[r] + b1v, 0.f));
    }
    __syncthreads();

    // ---- layer 2: K=128, + residual epilogue ----
    #pragma unroll
    for (int nt2 = 0; nt2 < 2; nt2++) {
        const int ntg = wv * 2 + nt2;
        const float b2v = ldf(b2, ntg * 16 + l15, isf);
        f32x4 c = {0.f, 0.f, 0.f, 0.f};
        #pragma unroll
        for (int ks = 0; ks < 4; ks++) {
            short8 a = *(const short8*)&hb[l15][ks * 32 + quad * 8];
            short8 b = *(const short8*)&w2s[(((size_t)(ntg * 4 + ks)) * 64 + lane) * 8];
            c = __builtin_amdgcn_mfma_f32_16x16x32_bf16(a, b, c, 0, 0, 0);
        }
        #pragma unroll
        for (int r = 0; r < 4; r++) {
            const int row = quad * 4 + r;
            const int col = ntg * 16 + l15;
            size_t o = (size_t)(n0 + row) * HD + col;
            float res = bf2f(node[o]) + fmaxf(c[r] + b2v, 0.f);
            if (OUT_BF16) ((u16*)outv)[o] = f2bf(res);
            else          ((float*)outv)[o] = res;
        }
    }
}

// ---------------------------------------------------------------------------
// CSR mean aggregation, fp32 accumulate, fp32 output. src bf16 or fp32.
// ---------------------------------------------------------------------------
template<int SRC_F32>
__global__ __launch_bounds__(128) void agg_kernel(
    const void* srcv, const u16* __restrict__ col,
    const int* __restrict__ rowptr, float* agg)
{
    __shared__ int cbuf[128];
    const int d = blockIdx.x;
    const int j = threadIdx.x;
    const int beg = rowptr[d], end = rowptr[d + 1];
    float acc = 0.f;
    for (int base = beg; base < end; base += 128) {
        const int m = min(128, end - base);
        if (j < m) cbuf[j] = (int)col[base + j];
        __syncthreads();
        #pragma unroll 4
        for (int e = 0; e < m; e++) {
            size_t o = (size_t)cbuf[e] * HD + j;
            acc += SRC_F32 ? ((const float*)srcv)[o] : bf2f(((const u16*)srcv)[o]);
        }
        __syncthreads();
    }
    const float deg = (float)(end - beg);
    agg[(size_t)d * HD + j] = acc / fmaxf(deg, 1.f);
}

// ---------------------------------------------------------------------------
// CSR build helpers
// ---------------------------------------------------------------------------
__global__ void zero_kernel(int* __restrict__ p, int n) {
    int i = blockIdx.x * blockDim.x + threadIdx.x;
    if (i < n) p[i] = 0;
}
__global__ void count_kernel(const int* __restrict__ dst, int* __restrict__ cnt, int ne) {
    int e = blockIdx.x * blockDim.x + threadIdx.x;
    if (e < ne) atomicAdd(&cnt[dst[e]], 1);
}
__global__ void fill_kernel(const int* __restrict__ src, const int* __restrict__ dst,
                            int* __restrict__ cur, u16* __restrict__ col, int ne) {
    int e = blockIdx.x * blockDim.x + threadIdx.x;
    if (e < ne) {
        int d = dst[e];
        int p = atomicAdd(&cur[d], 1);
        col[p] = (u16)src[e];
    }
}
__global__ void initcur_kernel(const int* __restrict__ rp_ll, const int* __restrict__ rp_aa,
                               const int* __restrict__ rp_la, int* __restrict__ cur) {
    int i = blockIdx.x * blockDim.x + threadIdx.x;
    if (i < N_LANEC) cur[i] = rp_ll[i];
    else if (i < N_LANEC + N_AGENTC) cur[i] = rp_aa[i - N_LANEC];
    else if (i < N_LANEC + 2 * N_AGENTC) cur[i] = rp_la[i - N_LANEC - N_AGENTC];
}

// in-place exclusive scan (LDS Hillis-Steele), one block per array
__global__ __launch_bounds__(1024) void scan3_kernel(
    int* __restrict__ rp_ll, int* __restrict__ rp_aa, int* __restrict__ rp_la)
{
    int* rp; int n;
    if (blockIdx.x == 0)      { rp = rp_ll; n = N_LANEC; }
    else if (blockIdx.x == 1) { rp = rp_aa; n = N_AGENTC; }
    else                      { rp = rp_la; n = N_AGENTC; }

    __shared__ int s[1024];
    __shared__ int carry;
    const int tid = threadIdx.x;
    if (tid == 0) carry = 0;
    __syncthreads();

    for (int base = 0; base < n; base += 1024) {
        const int i = base + tid;
        const int v = (i < n) ? rp[i] : 0;
        s[tid] = v;
        __syncthreads();
        for (int off = 1; off < 1024; off <<= 1) {
            int t = (tid >= off) ? s[tid - off] : 0;
            __syncthreads();
            s[tid] += t;
            __syncthreads();
        }
        const int incl = s[tid];
        const int c = carry;
        __syncthreads();
        if (i < n) rp[i] = c + incl - v;     // exclusive
        if (tid == 1023) carry = c + incl;
        __syncthreads();
    }
    if (tid == 0) rp[n] = carry;
}

// ---------------------------------------------------------------------------
extern "C" void kernel_launch(void* const* d_in, const int* in_sizes, int n_in,
                              void* d_out, int out_size, void* d_ws, size_t ws_size,
                              hipStream_t stream)
{
    const void* lane_pts   = d_in[0];
    const void* agent_hist = d_in[1];
    const int* e_ll = (const int*)d_in[2];   // [2][E]: row0 src, row1 dst
    const int* e_aa = (const int*)d_in[3];
    const int* e_la = (const int*)d_in[4];
    const void *lw1 = d_in[5],  *lb1 = d_in[6],  *lw2 = d_in[7],  *lb2 = d_in[8],
               *lw3 = d_in[9],  *lb3 = d_in[10];
    const void *aw1 = d_in[11], *ab1 = d_in[12], *aw2 = d_in[13], *ab2 = d_in[14],
               *aw3 = d_in[15], *ab3 = d_in[16];
    const void *llw1 = d_in[17], *llb1 = d_in[18], *llw2 = d_in[19], *llb2 = d_in[20];
    const void *aaw1 = d_in[21], *aab1 = d_in[22], *aaw2 = d_in[23], *aab2 = d_in[24];
    const void *law1 = d_in[25], *lab1 = d_in[26], *law2 = d_in[27], *lab2 = d_in[28];

    // ---- workspace layout (~8.7 MB): swizzled weights first (16B aligned) ----
    u16* sp = (u16*)d_ws;
    u16* lw2s  = sp; sp += 128 * HD;   // 16384
    u16* aw2s  = sp; sp += 128 * HD;
    u16* llw1s = sp; sp += 256 * HD;   // 32768
    u16* llw2s = sp; sp += 128 * HD;
    u16* aaw1s = sp; sp += 256 * HD;
    u16* aaw2s = sp; sp += 128 * HD;
    u16* law1s = sp; sp += 256 * HD;
    u16* law2s = sp; sp += 128 * HD;
    int* ip = (int*)sp;
    int* dflag = ip; ip += 4;
    int* rp_ll = ip; ip += N_LANEC + 1;
    int* rp_aa = ip; ip += N_AGENTC + 1;
    int* rp_la = ip; ip += N_AGENTC + 1;
    int* cur   = ip; ip += N_LANEC + 2 * N_AGENTC;
    u16* hp = (u16*)ip;
    u16* col_ll = hp; hp += E_LLC;
    u16* col_aa = hp; hp += E_AAC;
    u16* col_la = hp; hp += E_LAC;
    u16* lane_enc  = hp; hp += (size_t)N_LANEC * HD;   // bf16 encoder outputs
    u16* agent_enc = hp; hp += (size_t)N_AGENTC * HD;  // bf16; in-place aa-gnn

    float* out_lane  = (float*)d_out;
    float* out_agent = (float*)d_out + (size_t)N_LANEC * HD;

    const int NRP  = (N_LANEC + 1) + 2 * (N_AGENTC + 1);
    const int NCUR = N_LANEC + 2 * N_AGENTC;

    detect_kernel<<<1, 256, 0, stream>>>((const u32*)lane_pts, dflag);

    // ---- weight swizzles (frag-major bf16) ----
    swz_kernel<<<64, 256, 0, stream>>>(lw2,  lw2s,  2, 128 * HD, dflag);
    swz_kernel<<<64, 256, 0, stream>>>(aw2,  aw2s,  2, 128 * HD, dflag);
    swz_kernel<<<128, 256, 0, stream>>>(llw1, llw1s, 3, 256 * HD, dflag);
    swz_kernel<<<64, 256, 0, stream>>>(llw2, llw2s, 2, 128 * HD, dflag);
    swz_kernel<<<128, 256, 0, stream>>>(aaw1, aaw1s, 3, 256 * HD, dflag);
    swz_kernel<<<64, 256, 0, stream>>>(aaw2, aaw2s, 2, 128 * HD, dflag);
    swz_kernel<<<128, 256, 0, stream>>>(law1, law1s, 3, 256 * HD, dflag);
    swz_kernel<<<64, 256, 0, stream>>>(law2, law2s, 2, 128 * HD, dflag);

    // ---- CSR build ----
    zero_kernel<<<(NRP + 255) / 256, 256, 0, stream>>>(rp_ll, NRP);
    count_kernel<<<(E_LLC + 255) / 256, 256, 0, stream>>>(e_ll + E_LLC, rp_ll, E_LLC);
    count_kernel<<<(E_AAC + 255) / 256, 256, 0, stream>>>(e_aa + E_AAC, rp_aa, E_AAC);
    count_kernel<<<(E_LAC + 255) / 256, 256, 0, stream>>>(e_la + E_LAC, rp_la, E_LAC);
    scan3_kernel<<<3, 1024, 0, stream>>>(rp_ll, rp_aa, rp_la);
    initcur_kernel<<<(NCUR + 255) / 256, 256, 0, stream>>>(rp_ll, rp_aa, rp_la, cur);
    fill_kernel<<<(E_LLC + 255) / 256, 256, 0, stream>>>(e_ll, e_ll + E_LLC, cur,           col_ll, E_LLC);
    fill_kernel<<<(E_AAC + 255) / 256, 256, 0, stream>>>(e_aa, e_aa + E_AAC, cur + N_LANEC, col_aa, E_AAC);
    fill_kernel<<<(E_LAC + 255) / 256, 256, 0, stream>>>(e_la, e_la + E_LAC, cur + N_LANEC + N_AGENTC, col_la, E_LAC);

    // ---- encoders ----
    encode_kernel<<<N_LANEC / 4, 256, 0, stream>>>(lane_pts, lw1, lb1, lw2s, lb2, lw3, lb3, lane_enc, dflag);
    encode_kernel<<<N_AGENTC / 4, 256, 0, stream>>>(agent_hist, aw1, ab1, aw2s, ab2, aw3, ab3, agent_enc, dflag);

    // ---- lane-lane GNN: agg -> d_out lane region (fp32), gnn in place ----
    agg_kernel<0><<<N_LANEC, 128, 0, stream>>>(lane_enc, col_ll, rp_ll, out_lane);
    gnn_kernel<0><<<N_LANEC / 16, 256, 0, stream>>>(lane_enc, out_lane, llw1s, llb1, llw2s, llb2, out_lane, dflag);

    // ---- agent-agent GNN: mid result bf16 back into agent_enc ----
    agg_kernel<0><<<N_AGENTC, 128, 0, stream>>>(agent_enc, col_aa, rp_aa, out_agent);
    gnn_kernel<1><<<N_AGENTC / 16, 256, 0, stream>>>(agent_enc, out_agent, aaw1s, aab1, aaw2s, aab2, agent_enc, dflag);

    // ---- lane->agent GNN: agg from final lane (fp32); final fp32 to d_out ----
    agg_kernel<1><<<N_AGENTC, 128, 0, stream>>>(out_lane, col_la, rp_la, out_agent);
    gnn_kernel<0><<<N_AGENTC / 16, 256, 0, stream>>>(agent_enc, out_agent, law1s, lab1, law2s, lab2, out_agent, dflag);
}